// Round 1
// baseline (1294.697 us; speedup 1.0000x reference)
//
#include <hip/hip_runtime.h>

#define D 128
#define BN 32          // nodes per block in node_gemm
#define KC 32          // K-chunk

// ---------------------------------------------------------------------------
// rel_kernel: rf = rel_emb @ W_fwd^T (to ws), rel_out = rel_emb @ W_rel^T (d_out tail)
// one block per relation row, 128 threads (one per output col)
// ---------------------------------------------------------------------------
__global__ __launch_bounds__(128) void rel_kernel(
    const float* __restrict__ rel, const float* __restrict__ Wf,
    const float* __restrict__ Wr, float* __restrict__ rf,
    float* __restrict__ rel_out) {
  __shared__ float row[D];
  const int r = blockIdx.x;
  const int c = threadIdx.x;
  row[c] = rel[r * D + c];
  __syncthreads();
  float af = 0.f, ar = 0.f;
  #pragma unroll 8
  for (int k = 0; k < D; ++k) {
    const float xv = row[k];
    af += xv * Wf[c * D + k];
    ar += xv * Wr[c * D + k];
  }
  rf[r * D + c] = af;
  rel_out[r * D + c] = ar;
}

// ---------------------------------------------------------------------------
// node_gemm: out[n,:] = x[n,:] @ Wself^T + bias ; xf[n,:] = x[n,:] @ Wfwd^T
// block = 256 threads, BN=32 nodes. Weights staged transposed in LDS in
// KC-chunks (pad +1 -> 2-way bank aliasing = free). Thread (tc=tid&63,
// tr=tid>>6) computes cols {tc, tc+64} for 8 nodes {tr*8..tr*8+7}, both mats.
// x reads are wave-uniform LDS broadcasts (tr uniform within wave).
// ---------------------------------------------------------------------------
__global__ __launch_bounds__(256) void node_gemm(
    const float* __restrict__ x, const float* __restrict__ Wself,
    const float* __restrict__ Wfwd, const float* __restrict__ bias,
    float* __restrict__ out, float* __restrict__ xf) {
  __shared__ float xs[BN][D];            // 16 KB
  __shared__ float wa[KC][D + 1];        // 16.5 KB  (Wself^T chunk)
  __shared__ float wb[KC][D + 1];        // 16.5 KB  (Wfwd^T chunk)

  const int tid = threadIdx.x;
  const int n0 = blockIdx.x * BN;

  // stage x tile: 32*128 floats = 1024 float4, 4 per thread, fully coalesced
  {
    const float4* xg = (const float4*)(x + (size_t)n0 * D);
    float4* xl = (float4*)&xs[0][0];
    #pragma unroll
    for (int p = 0; p < 4; ++p) xl[p * 256 + tid] = xg[p * 256 + tid];
  }

  const int tc = tid & 63;
  const int tr = tid >> 6;

  float acc_a0[8], acc_a1[8], acc_b0[8], acc_b1[8];
  #pragma unroll
  for (int i = 0; i < 8; ++i) { acc_a0[i] = acc_a1[i] = acc_b0[i] = acc_b1[i] = 0.f; }

  for (int kc = 0; kc < D; kc += KC) {
    __syncthreads();   // also covers the x-tile staging on first iteration
    // stage weight chunks transposed: per mat 1024 float4 global loads
    #pragma unroll
    for (int p = 0; p < 4; ++p) {
      const int l = p * 256 + tid;          // 0..1023
      const int c = l >> 3;                 // 0..127
      const int kq = (l & 7) * 4;           // 0,4,...,28
      const float4 va = *(const float4*)(Wself + c * D + kc + kq);
      const float4 vb = *(const float4*)(Wfwd  + c * D + kc + kq);
      wa[kq + 0][c] = va.x; wa[kq + 1][c] = va.y; wa[kq + 2][c] = va.z; wa[kq + 3][c] = va.w;
      wb[kq + 0][c] = vb.x; wb[kq + 1][c] = vb.y; wb[kq + 2][c] = vb.z; wb[kq + 3][c] = vb.w;
    }
    __syncthreads();

    #pragma unroll
    for (int k = 0; k < KC; ++k) {
      const float wa0 = wa[k][tc], wa1 = wa[k][tc + 64];
      const float wb0 = wb[k][tc], wb1 = wb[k][tc + 64];
      #pragma unroll
      for (int i = 0; i < 8; ++i) {
        const float xv = xs[tr * 8 + i][kc + k];   // wave-uniform broadcast
        acc_a0[i] += xv * wa0;
        acc_a1[i] += xv * wa1;
        acc_b0[i] += xv * wb0;
        acc_b1[i] += xv * wb1;
      }
    }
  }

  const float b0 = bias[tc], b1 = bias[tc + 64];
  #pragma unroll
  for (int i = 0; i < 8; ++i) {
    const size_t n = (size_t)(n0 + tr * 8 + i);
    out[n * D + tc]      = acc_a0[i] + b0;
    out[n * D + tc + 64] = acc_a1[i] + b1;
    xf[n * D + tc]       = acc_b0[i];
    xf[n * D + tc + 64]  = acc_b1[i];
  }
}

// ---------------------------------------------------------------------------
// edge_scatter: out[dst,:] += ew[e] * (xf[src,:] - rf[et,:])
// 256 threads = 8 edges/block, 32 lanes per edge, float4 per lane, 4 atomics
// ---------------------------------------------------------------------------
__global__ __launch_bounds__(256) void edge_scatter(
    const float* __restrict__ xf, const float* __restrict__ rf,
    const int* __restrict__ ei, const int* __restrict__ etype,
    const float* __restrict__ ew, float* __restrict__ out, int nE) {
  const int e = blockIdx.x * 8 + (threadIdx.x >> 5);
  if (e >= nE) return;
  const int lane = threadIdx.x & 31;
  const int s = ei[e];
  const int d = ei[nE + e];
  const int t = etype[e];
  const float w = ew[e];
  const float4 a = ((const float4*)(xf + (size_t)s * D))[lane];
  const float4 b = ((const float4*)(rf + (size_t)t * D))[lane];
  float* o = out + (size_t)d * D + lane * 4;
  atomicAdd(o + 0, w * (a.x - b.x));
  atomicAdd(o + 1, w * (a.y - b.y));
  atomicAdd(o + 2, w * (a.z - b.z));
  atomicAdd(o + 3, w * (a.w - b.w));
}

// ---------------------------------------------------------------------------
extern "C" void kernel_launch(void* const* d_in, const int* in_sizes, int n_in,
                              void* d_out, int out_size, void* d_ws, size_t ws_size,
                              hipStream_t stream) {
  const float* x      = (const float*)d_in[0];
  const int*   ei     = (const int*)d_in[1];
  const int*   etype  = (const int*)d_in[2];
  const float* rel    = (const float*)d_in[3];
  const float* ew     = (const float*)d_in[4];
  const float* Wself  = (const float*)d_in[5];
  const float* Wfwd   = (const float*)d_in[6];
  const float* Wrel   = (const float*)d_in[7];
  const float* bias   = (const float*)d_in[8];

  const int nN = in_sizes[0] / D;       // 100000
  const int nE = in_sizes[2];           // 625000
  const int nR = in_sizes[3] / D;       // 200

  float* out     = (float*)d_out;                    // nN*D
  float* rel_out = (float*)d_out + (size_t)nN * D;   // nR*D
  float* xf      = (float*)d_ws;                     // nN*D
  float* rf      = (float*)d_ws + (size_t)nN * D;    // nR*D

  // rf + rel_out (independent of the rest, tiny)
  rel_kernel<<<nR, 128, 0, stream>>>(rel, Wfwd, Wrel, rf, rel_out);

  // out = x@Wself^T + bias ; xf = x@Wfwd^T   (nN % BN == 0 for nN=100000)
  node_gemm<<<nN / BN, 256, 0, stream>>>(x, Wself, Wfwd, bias, out, xf);

  // scatter-add messages
  edge_scatter<<<(nE + 7) / 8, 256, 0, stream>>>(xf, rf, ei, etype, ew, out, nE);
}

// Round 2
// 393.415 us; speedup vs baseline: 3.2909x; 3.2909x over previous
//
#include <hip/hip_runtime.h>

#define D 128
#define BN 32          // nodes per block in node_gemm
#define KC 32          // K-chunk
#define SCAN_B 256

// ---------------------------------------------------------------------------
// rel_kernel: rf = rel_emb @ W_fwd^T (to ws), rel_out = rel_emb @ W_rel^T (d_out tail)
// ---------------------------------------------------------------------------
__global__ __launch_bounds__(128) void rel_kernel(
    const float* __restrict__ rel, const float* __restrict__ Wf,
    const float* __restrict__ Wr, float* __restrict__ rf,
    float* __restrict__ rel_out) {
  __shared__ float row[D];
  const int r = blockIdx.x;
  const int c = threadIdx.x;
  row[c] = rel[r * D + c];
  __syncthreads();
  float af = 0.f, ar = 0.f;
  #pragma unroll 8
  for (int k = 0; k < D; ++k) {
    const float xv = row[k];
    af += xv * Wf[c * D + k];
    ar += xv * Wr[c * D + k];
  }
  rf[r * D + c] = af;
  rel_out[r * D + c] = ar;
}

// ---------------------------------------------------------------------------
// node_gemm: out[n,:] = x[n,:] @ Wself^T + bias ; xf[n,:] = x[n,:] @ Wfwd^T
// (unchanged from round 1)
// ---------------------------------------------------------------------------
__global__ __launch_bounds__(256) void node_gemm(
    const float* __restrict__ x, const float* __restrict__ Wself,
    const float* __restrict__ Wfwd, const float* __restrict__ bias,
    float* __restrict__ out, float* __restrict__ xf) {
  __shared__ float xs[BN][D];
  __shared__ float wa[KC][D + 1];
  __shared__ float wb[KC][D + 1];

  const int tid = threadIdx.x;
  const int n0 = blockIdx.x * BN;

  {
    const float4* xg = (const float4*)(x + (size_t)n0 * D);
    float4* xl = (float4*)&xs[0][0];
    #pragma unroll
    for (int p = 0; p < 4; ++p) xl[p * 256 + tid] = xg[p * 256 + tid];
  }

  const int tc = tid & 63;
  const int tr = tid >> 6;

  float acc_a0[8], acc_a1[8], acc_b0[8], acc_b1[8];
  #pragma unroll
  for (int i = 0; i < 8; ++i) { acc_a0[i] = acc_a1[i] = acc_b0[i] = acc_b1[i] = 0.f; }

  for (int kc = 0; kc < D; kc += KC) {
    __syncthreads();
    #pragma unroll
    for (int p = 0; p < 4; ++p) {
      const int l = p * 256 + tid;
      const int c = l >> 3;
      const int kq = (l & 7) * 4;
      const float4 va = *(const float4*)(Wself + c * D + kc + kq);
      const float4 vb = *(const float4*)(Wfwd  + c * D + kc + kq);
      wa[kq + 0][c] = va.x; wa[kq + 1][c] = va.y; wa[kq + 2][c] = va.z; wa[kq + 3][c] = va.w;
      wb[kq + 0][c] = vb.x; wb[kq + 1][c] = vb.y; wb[kq + 2][c] = vb.z; wb[kq + 3][c] = vb.w;
    }
    __syncthreads();

    #pragma unroll
    for (int k = 0; k < KC; ++k) {
      const float wa0 = wa[k][tc], wa1 = wa[k][tc + 64];
      const float wb0 = wb[k][tc], wb1 = wb[k][tc + 64];
      #pragma unroll
      for (int i = 0; i < 8; ++i) {
        const float xv = xs[tr * 8 + i][kc + k];
        acc_a0[i] += xv * wa0;
        acc_a1[i] += xv * wa1;
        acc_b0[i] += xv * wb0;
        acc_b1[i] += xv * wb1;
      }
    }
  }

  const float b0 = bias[tc], b1 = bias[tc + 64];
  #pragma unroll
  for (int i = 0; i < 8; ++i) {
    const size_t n = (size_t)(n0 + tr * 8 + i);
    out[n * D + tc]      = acc_a0[i] + b0;
    out[n * D + tc + 64] = acc_a1[i] + b1;
    xf[n * D + tc]       = acc_b0[i];
    xf[n * D + tc + 64]  = acc_b1[i];
  }
}

// ---------------------------------------------------------------------------
// CSR build: histogram -> exclusive scan (3 kernels) -> fill (atomic cursor)
// ---------------------------------------------------------------------------
__global__ void hist_kernel(const int* __restrict__ dst, int* __restrict__ deg, int nE) {
  const int e = blockIdx.x * blockDim.x + threadIdx.x;
  if (e < nE) atomicAdd(&deg[dst[e]], 1);
}

__global__ __launch_bounds__(SCAN_B) void scan_pass1(
    const int* __restrict__ deg, int* __restrict__ bsum, int n) {
  __shared__ int sd[SCAN_B];
  const int i = blockIdx.x * SCAN_B + threadIdx.x;
  sd[threadIdx.x] = (i < n) ? deg[i] : 0;
  __syncthreads();
  for (int s = SCAN_B / 2; s > 0; s >>= 1) {
    if (threadIdx.x < s) sd[threadIdx.x] += sd[threadIdx.x + s];
    __syncthreads();
  }
  if (threadIdx.x == 0) bsum[blockIdx.x] = sd[0];
}

__global__ __launch_bounds__(1024) void scan_pass2(int* __restrict__ bsum, int nb) {
  __shared__ int sd[1024];
  const int t = threadIdx.x;
  const int v = (t < nb) ? bsum[t] : 0;
  sd[t] = v;
  __syncthreads();
  for (int off = 1; off < 1024; off <<= 1) {
    const int add = (t >= off) ? sd[t - off] : 0;
    __syncthreads();
    sd[t] += add;
    __syncthreads();
  }
  if (t < nb) bsum[t] = sd[t] - v;   // exclusive
}

__global__ __launch_bounds__(SCAN_B) void scan_pass3(
    int* __restrict__ deg_offs, const int* __restrict__ bsum, int n) {
  __shared__ int sd[SCAN_B];
  const int i = blockIdx.x * SCAN_B + threadIdx.x;
  const int t = threadIdx.x;
  const int v = (i < n) ? deg_offs[i] : 0;
  sd[t] = v;
  __syncthreads();
  for (int off = 1; off < SCAN_B; off <<= 1) {
    const int add = (t >= off) ? sd[t - off] : 0;
    __syncthreads();
    sd[t] += add;
    __syncthreads();
  }
  if (i < n) deg_offs[i] = sd[t] - v + bsum[blockIdx.x];   // exclusive global
}

__global__ void fill_kernel(const int* __restrict__ dst, int* __restrict__ cursor,
                            int* __restrict__ perm, int nE) {
  const int e = blockIdx.x * blockDim.x + threadIdx.x;
  if (e < nE) {
    const int p = atomicAdd(&cursor[dst[e]], 1);
    perm[p] = e;
  }
}

// ---------------------------------------------------------------------------
// csr_agg: out[n,:] += sum_{e in bucket(n)} ew[e]*(xf[src[e],:] - rf[et[e],:])
// 32 lanes per node, float4/lane. Edge metadata loaded 32-at-a-time in
// parallel by the subgroup, then shuffle-broadcast (no dependent-load chain).
// After fill, offs[n] = inclusive end; start = offs[n-1] (0 for n=0).
// ---------------------------------------------------------------------------
__global__ __launch_bounds__(256) void csr_agg(
    const float4* __restrict__ xf4, const float4* __restrict__ rf4,
    const int* __restrict__ perm, const int* __restrict__ src,
    const int* __restrict__ et, const float* __restrict__ ew,
    const int* __restrict__ offs, float4* __restrict__ out4, int nN) {
  const int n = blockIdx.x * 8 + (threadIdx.x >> 5);
  if (n >= nN) return;
  const int lane = threadIdx.x & 31;
  const int end = offs[n];
  const int start = (n == 0) ? 0 : offs[n - 1];

  float4 acc = make_float4(0.f, 0.f, 0.f, 0.f);
  for (int base = start; base < end; base += 32) {
    int m = end - base;
    if (m > 32) m = 32;
    int sv = 0, tv = 0;
    float wv = 0.f;
    if (lane < m) {
      const int e = perm[base + lane];
      sv = src[e];
      tv = et[e];
      wv = ew[e];
    }
    for (int j = 0; j < m; ++j) {
      const int s = __shfl(sv, j, 32);
      const int t = __shfl(tv, j, 32);
      const float w = __shfl(wv, j, 32);
      const float4 a = xf4[(size_t)s * 32 + lane];
      const float4 b = rf4[(size_t)t * 32 + lane];
      acc.x += w * (a.x - b.x);
      acc.y += w * (a.y - b.y);
      acc.z += w * (a.z - b.z);
      acc.w += w * (a.w - b.w);
    }
  }
  const size_t o = (size_t)n * 32 + lane;
  float4 c = out4[o];
  c.x += acc.x; c.y += acc.y; c.z += acc.z; c.w += acc.w;
  out4[o] = c;
}

// ---------------------------------------------------------------------------
// Fallback (round-1 path) if ws_size is too small for the CSR buffers
// ---------------------------------------------------------------------------
__global__ __launch_bounds__(256) void edge_scatter(
    const float* __restrict__ xf, const float* __restrict__ rf,
    const int* __restrict__ ei, const int* __restrict__ etype,
    const float* __restrict__ ew, float* __restrict__ out, int nE) {
  const int e = blockIdx.x * 8 + (threadIdx.x >> 5);
  if (e >= nE) return;
  const int lane = threadIdx.x & 31;
  const int s = ei[e];
  const int d = ei[nE + e];
  const int t = etype[e];
  const float w = ew[e];
  const float4 a = ((const float4*)(xf + (size_t)s * D))[lane];
  const float4 b = ((const float4*)(rf + (size_t)t * D))[lane];
  float* o = out + (size_t)d * D + lane * 4;
  atomicAdd(o + 0, w * (a.x - b.x));
  atomicAdd(o + 1, w * (a.y - b.y));
  atomicAdd(o + 2, w * (a.z - b.z));
  atomicAdd(o + 3, w * (a.w - b.w));
}

// ---------------------------------------------------------------------------
extern "C" void kernel_launch(void* const* d_in, const int* in_sizes, int n_in,
                              void* d_out, int out_size, void* d_ws, size_t ws_size,
                              hipStream_t stream) {
  const float* x      = (const float*)d_in[0];
  const int*   ei     = (const int*)d_in[1];
  const int*   etype  = (const int*)d_in[2];
  const float* rel    = (const float*)d_in[3];
  const float* ew     = (const float*)d_in[4];
  const float* Wself  = (const float*)d_in[5];
  const float* Wfwd   = (const float*)d_in[6];
  const float* Wrel   = (const float*)d_in[7];
  const float* bias   = (const float*)d_in[8];

  const int nN = in_sizes[0] / D;       // 100000
  const int nE = in_sizes[2];           // 625000
  const int nR = in_sizes[3] / D;       // 200

  float* out     = (float*)d_out;
  float* rel_out = (float*)d_out + (size_t)nN * D;

  // workspace carve-up (256B-aligned segments)
  char* w = (char*)d_ws;
  size_t off = 0;
  auto carve = [&](size_t bytes) {
    char* p = w + off;
    off = (off + bytes + 255) & ~(size_t)255;
    return p;
  };
  float* xf   = (float*)carve((size_t)nN * D * sizeof(float));
  float* rf   = (float*)carve((size_t)nR * D * sizeof(float));
  int*   offs = (int*)carve((size_t)nN * sizeof(int));
  int*   perm = (int*)carve((size_t)nE * sizeof(int));
  int*   bsum = (int*)carve(1024 * sizeof(int));
  const size_t need = off;

  const int* dst = ei + nE;             // edge_index row 1
  const int nb = (nN + SCAN_B - 1) / SCAN_B;   // scan blocks (391 <= 1024)

  // rf + rel_out (tiny, independent)
  rel_kernel<<<nR, 128, 0, stream>>>(rel, Wfwd, Wrel, rf, rel_out);

  // out = x@Wself^T + bias ; xf = x@Wfwd^T
  node_gemm<<<nN / BN, 256, 0, stream>>>(x, Wself, Wfwd, bias, out, xf);

  if (need <= ws_size && nb <= 1024) {
    // ---- CSR build (counting sort by dst) ----
    hipMemsetAsync(offs, 0, (size_t)nN * sizeof(int), stream);
    hist_kernel<<<(nE + 255) / 256, 256, 0, stream>>>(dst, offs, nE);
    scan_pass1<<<nb, SCAN_B, 0, stream>>>(offs, bsum, nN);
    scan_pass2<<<1, 1024, 0, stream>>>(bsum, nb);
    scan_pass3<<<nb, SCAN_B, 0, stream>>>(offs, bsum, nN);
    fill_kernel<<<(nE + 255) / 256, 256, 0, stream>>>(dst, offs, perm, nE);
    // ---- atomic-free aggregation, one owner per node ----
    csr_agg<<<(nN + 7) / 8, 256, 0, stream>>>(
        (const float4*)xf, (const float4*)rf, perm, ei, etype, ew, offs,
        (float4*)out, nN);
  } else {
    edge_scatter<<<(nE + 7) / 8, 256, 0, stream>>>(xf, rf, ei, etype, ew, out, nE);
  }
}

// Round 3
// 291.775 us; speedup vs baseline: 4.4373x; 1.3483x over previous
//
#include <hip/hip_runtime.h>

#define D 128
#define SCAN_B 256

typedef short bf16x8 __attribute__((ext_vector_type(8)));
typedef float f32x4 __attribute__((ext_vector_type(4)));

static __device__ __forceinline__ unsigned short f2bf(float f) {
  union { float f; unsigned u; } v; v.f = f;
  return (unsigned short)((v.u + 0x7FFF + ((v.u >> 16) & 1)) >> 16);   // RNE
}
static __device__ __forceinline__ float bf2f(unsigned short h) {
  union { unsigned u; float f; } v; v.u = ((unsigned)h) << 16;
  return v.f;
}

// ---------------------------------------------------------------------------
// w_prep: convert Wself/Wfwd fp32 -> bf16, pre-swizzled into MFMA B-fragment
// order. frag = ((mat*8 + ct)*4 + kt); lane (q=lane>>4, r=lane&15) holds
// W[ct*16+r][kt*32+q*8 + j] j=0..7 at Wb[frag*512 + lane*8]. One 16B load
// per B-frag in the GEMM, zero per-block conversion cost.
// ---------------------------------------------------------------------------
__global__ __launch_bounds__(256) void w_prep(
    const float* __restrict__ Wself, const float* __restrict__ Wfwd,
    unsigned short* __restrict__ Wb) {
  const int g = blockIdx.x * 256 + threadIdx.x;   // 0..4095
  const int frag = g >> 6;
  const int lane = g & 63;
  const int mat = frag >> 5;
  const int ct  = (frag >> 2) & 7;
  const int kt  = frag & 3;
  const int q = lane >> 4, r = lane & 15;
  const float* W = mat ? Wfwd : Wself;
  const float* src = W + (ct * 16 + r) * D + kt * 32 + q * 8;
  unsigned short* dst = Wb + frag * 512 + lane * 8;
  #pragma unroll
  for (int j = 0; j < 8; ++j) dst[j] = f2bf(src[j]);
}

// ---------------------------------------------------------------------------
// rel_kernel: rfb = bf16(rel @ W_fwd^T) (ws), rel_out = rel @ W_rel^T (d_out)
// ---------------------------------------------------------------------------
__global__ __launch_bounds__(128) void rel_kernel(
    const float* __restrict__ rel, const float* __restrict__ Wf,
    const float* __restrict__ Wr, unsigned short* __restrict__ rfb,
    float* __restrict__ rel_out) {
  __shared__ float row[D];
  const int r = blockIdx.x;
  const int c = threadIdx.x;
  row[c] = rel[r * D + c];
  __syncthreads();
  float af = 0.f, ar = 0.f;
  #pragma unroll 8
  for (int k = 0; k < D; ++k) {
    const float xv = row[k];
    af += xv * Wf[c * D + k];
    ar += xv * Wr[c * D + k];
  }
  rfb[r * D + c] = f2bf(af);
  rel_out[r * D + c] = ar;
}

// ---------------------------------------------------------------------------
// node_mfma: out = x@Wself^T + bias (fp32), xfb = bf16(x@Wfwd^T)
// 64 nodes/block, 4 waves, wave w owns rows n0+w*16..+15, all 128 cols, both
// mats: 8 col-tiles x 2 = 16 accumulators (64 AGPRs). A-frag: inline fp32->
// bf16 cast (reused over 16 MFMAs). B-frag: one 16B load from Wb (L2-hot).
// No LDS.  C/D layout: col=lane&15, row=(lane>>4)*4+reg.
// ---------------------------------------------------------------------------
__global__ __launch_bounds__(256) void node_mfma(
    const float* __restrict__ x, const unsigned short* __restrict__ Wb,
    const float* __restrict__ bias, float* __restrict__ out,
    unsigned short* __restrict__ xfb, int nN) {
  const int tid = threadIdx.x;
  const int w = tid >> 6, lane = tid & 63;
  const int q = lane >> 4, r = lane & 15;
  const int n0 = blockIdx.x * 64 + w * 16;

  f32x4 accS[8], accF[8];
  #pragma unroll
  for (int ct = 0; ct < 8; ++ct) {
    accS[ct] = (f32x4)0.f;
    accF[ct] = (f32x4)0.f;
  }

  int arow = n0 + r;
  if (arow >= nN) arow = nN - 1;   // clamp (stores are guarded)
  const float* xrow = x + (size_t)arow * D;

  #pragma unroll
  for (int kt = 0; kt < 4; ++kt) {
    const float* xp = xrow + kt * 32 + q * 8;
    const float4 x0 = *(const float4*)xp;
    const float4 x1 = *(const float4*)(xp + 4);
    bf16x8 a;
    a[0] = (short)f2bf(x0.x); a[1] = (short)f2bf(x0.y);
    a[2] = (short)f2bf(x0.z); a[3] = (short)f2bf(x0.w);
    a[4] = (short)f2bf(x1.x); a[5] = (short)f2bf(x1.y);
    a[6] = (short)f2bf(x1.z); a[7] = (short)f2bf(x1.w);
    #pragma unroll
    for (int ct = 0; ct < 8; ++ct) {
      const bf16x8 bS = *(const bf16x8*)(Wb + ((0 * 8 + ct) * 4 + kt) * 512 + lane * 8);
      const bf16x8 bF = *(const bf16x8*)(Wb + ((1 * 8 + ct) * 4 + kt) * 512 + lane * 8);
      accS[ct] = __builtin_amdgcn_mfma_f32_16x16x32_bf16(a, bS, accS[ct], 0, 0, 0);
      accF[ct] = __builtin_amdgcn_mfma_f32_16x16x32_bf16(a, bF, accF[ct], 0, 0, 0);
    }
  }

  #pragma unroll
  for (int ct = 0; ct < 8; ++ct) {
    const int col = ct * 16 + r;
    const float bv = bias[col];
    #pragma unroll
    for (int reg = 0; reg < 4; ++reg) {
      const int row = n0 + q * 4 + reg;
      if (row < nN) {
        out[(size_t)row * D + col] = accS[ct][reg] + bv;
        xfb[(size_t)row * D + col] = f2bf(accF[ct][reg]);
      }
    }
  }
}

// ---------------------------------------------------------------------------
// CSR build: histogram -> exclusive scan (3 kernels) -> fill (atomic cursor)
// ---------------------------------------------------------------------------
__global__ void hist_kernel(const int* __restrict__ dst, int* __restrict__ deg, int nE) {
  const int e = blockIdx.x * blockDim.x + threadIdx.x;
  if (e < nE) atomicAdd(&deg[dst[e]], 1);
}

__global__ __launch_bounds__(SCAN_B) void scan_pass1(
    const int* __restrict__ deg, int* __restrict__ bsum, int n) {
  __shared__ int sd[SCAN_B];
  const int i = blockIdx.x * SCAN_B + threadIdx.x;
  sd[threadIdx.x] = (i < n) ? deg[i] : 0;
  __syncthreads();
  for (int s = SCAN_B / 2; s > 0; s >>= 1) {
    if (threadIdx.x < s) sd[threadIdx.x] += sd[threadIdx.x + s];
    __syncthreads();
  }
  if (threadIdx.x == 0) bsum[blockIdx.x] = sd[0];
}

__global__ __launch_bounds__(1024) void scan_pass2(int* __restrict__ bsum, int nb) {
  __shared__ int sd[1024];
  const int t = threadIdx.x;
  const int v = (t < nb) ? bsum[t] : 0;
  sd[t] = v;
  __syncthreads();
  for (int off = 1; off < 1024; off <<= 1) {
    const int add = (t >= off) ? sd[t - off] : 0;
    __syncthreads();
    sd[t] += add;
    __syncthreads();
  }
  if (t < nb) bsum[t] = sd[t] - v;   // exclusive
}

__global__ __launch_bounds__(SCAN_B) void scan_pass3(
    int* __restrict__ deg_offs, const int* __restrict__ bsum, int n) {
  __shared__ int sd[SCAN_B];
  const int i = blockIdx.x * SCAN_B + threadIdx.x;
  const int t = threadIdx.x;
  const int v = (i < n) ? deg_offs[i] : 0;
  sd[t] = v;
  __syncthreads();
  for (int off = 1; off < SCAN_B; off <<= 1) {
    const int add = (t >= off) ? sd[t - off] : 0;
    __syncthreads();
    sd[t] += add;
    __syncthreads();
  }
  if (i < n) deg_offs[i] = sd[t] - v + bsum[blockIdx.x];   // exclusive global
}

__global__ void fill_kernel(const int* __restrict__ dst, int* __restrict__ cursor,
                            int* __restrict__ perm, int nE) {
  const int e = blockIdx.x * blockDim.x + threadIdx.x;
  if (e < nE) {
    const int p = atomicAdd(&cursor[dst[e]], 1);
    perm[p] = e;
  }
}

// ---------------------------------------------------------------------------
// csr_agg: out[n,:] += sum_{e in bucket(n)} ew[e]*(xf[src[e],:] - rf[et[e],:])
// 32 lanes/node, bf16 gathers (ushort4 = 8B/lane), fp32 accumulate, one
// non-atomic RMW of out per node.
// ---------------------------------------------------------------------------
__global__ __launch_bounds__(256) void csr_agg(
    const unsigned short* __restrict__ xfb, const unsigned short* __restrict__ rfb,
    const int* __restrict__ perm, const int* __restrict__ src,
    const int* __restrict__ et, const float* __restrict__ ew,
    const int* __restrict__ offs, float4* __restrict__ out4, int nN) {
  const int n = blockIdx.x * 8 + (threadIdx.x >> 5);
  if (n >= nN) return;
  const int lane = threadIdx.x & 31;
  const int end = offs[n];
  const int start = (n == 0) ? 0 : offs[n - 1];

  float4 acc = make_float4(0.f, 0.f, 0.f, 0.f);
  for (int base = start; base < end; base += 32) {
    int m = end - base;
    if (m > 32) m = 32;
    int sv = 0, tv = 0;
    float wv = 0.f;
    if (lane < m) {
      const int e = perm[base + lane];
      sv = src[e];
      tv = et[e];
      wv = ew[e];
    }
    for (int j = 0; j < m; ++j) {
      const int s = __shfl(sv, j, 32);
      const int t = __shfl(tv, j, 32);
      const float wgt = __shfl(wv, j, 32);
      const ushort4 a = ((const ushort4*)(xfb + (size_t)s * D))[lane];
      const ushort4 b = ((const ushort4*)(rfb + (size_t)t * D))[lane];
      acc.x += wgt * (bf2f(a.x) - bf2f(b.x));
      acc.y += wgt * (bf2f(a.y) - bf2f(b.y));
      acc.z += wgt * (bf2f(a.z) - bf2f(b.z));
      acc.w += wgt * (bf2f(a.w) - bf2f(b.w));
    }
  }
  const size_t o = (size_t)n * 32 + lane;
  float4 c = out4[o];
  c.x += acc.x; c.y += acc.y; c.z += acc.z; c.w += acc.w;
  out4[o] = c;
}

// ---------------------------------------------------------------------------
// Fallback if ws too small: atomic scatter from bf16 xf/rf
// ---------------------------------------------------------------------------
__global__ __launch_bounds__(256) void edge_scatter(
    const unsigned short* __restrict__ xfb, const unsigned short* __restrict__ rfb,
    const int* __restrict__ ei, const int* __restrict__ etype,
    const float* __restrict__ ew, float* __restrict__ out, int nE) {
  const int e = blockIdx.x * 8 + (threadIdx.x >> 5);
  if (e >= nE) return;
  const int lane = threadIdx.x & 31;
  const int s = ei[e];
  const int d = ei[nE + e];
  const int t = etype[e];
  const float w = ew[e];
  const ushort4 a = ((const ushort4*)(xfb + (size_t)s * D))[lane];
  const ushort4 b = ((const ushort4*)(rfb + (size_t)t * D))[lane];
  float* o = out + (size_t)d * D + lane * 4;
  atomicAdd(o + 0, w * (bf2f(a.x) - bf2f(b.x)));
  atomicAdd(o + 1, w * (bf2f(a.y) - bf2f(b.y)));
  atomicAdd(o + 2, w * (bf2f(a.z) - bf2f(b.z)));
  atomicAdd(o + 3, w * (bf2f(a.w) - bf2f(b.w)));
}

// ---------------------------------------------------------------------------
extern "C" void kernel_launch(void* const* d_in, const int* in_sizes, int n_in,
                              void* d_out, int out_size, void* d_ws, size_t ws_size,
                              hipStream_t stream) {
  const float* x      = (const float*)d_in[0];
  const int*   ei     = (const int*)d_in[1];
  const int*   etype  = (const int*)d_in[2];
  const float* rel    = (const float*)d_in[3];
  const float* ew     = (const float*)d_in[4];
  const float* Wself  = (const float*)d_in[5];
  const float* Wfwd   = (const float*)d_in[6];
  const float* Wrel   = (const float*)d_in[7];
  const float* bias   = (const float*)d_in[8];

  const int nN = in_sizes[0] / D;       // 100000
  const int nE = in_sizes[2];           // 625000
  const int nR = in_sizes[3] / D;       // 200

  float* out     = (float*)d_out;
  float* rel_out = (float*)d_out + (size_t)nN * D;

  // workspace carve-up (256B-aligned)
  char* w = (char*)d_ws;
  size_t off = 0;
  auto carve = [&](size_t bytes) {
    char* p = w + off;
    off = (off + bytes + 255) & ~(size_t)255;
    return p;
  };
  unsigned short* xfb = (unsigned short*)carve((size_t)nN * D * sizeof(unsigned short));
  unsigned short* rfb = (unsigned short*)carve((size_t)nR * D * sizeof(unsigned short));
  unsigned short* Wb  = (unsigned short*)carve(2 * 8 * 4 * 512 * sizeof(unsigned short));
  int* offs = (int*)carve((size_t)nN * sizeof(int));
  int* perm = (int*)carve((size_t)nE * sizeof(int));
  int* bsum = (int*)carve(1024 * sizeof(int));
  const size_t need = off;

  const int* dst = ei + nE;
  const int nb = (nN + SCAN_B - 1) / SCAN_B;

  // weight prep + relation path (tiny)
  w_prep<<<16, 256, 0, stream>>>(Wself, Wfwd, Wb);
  rel_kernel<<<nR, 128, 0, stream>>>(rel, Wfwd, Wrel, rfb, rel_out);

  // out = x@Wself^T + bias ; xfb = bf16(x@Wfwd^T)
  node_mfma<<<(nN + 63) / 64, 256, 0, stream>>>(x, Wb, bias, out, xfb, nN);

  if (need <= ws_size && nb <= 1024) {
    hipMemsetAsync(offs, 0, (size_t)nN * sizeof(int), stream);
    hist_kernel<<<(nE + 255) / 256, 256, 0, stream>>>(dst, offs, nE);
    scan_pass1<<<nb, SCAN_B, 0, stream>>>(offs, bsum, nN);
    scan_pass2<<<1, 1024, 0, stream>>>(bsum, nb);
    scan_pass3<<<nb, SCAN_B, 0, stream>>>(offs, bsum, nN);
    fill_kernel<<<(nE + 255) / 256, 256, 0, stream>>>(dst, offs, perm, nE);
    csr_agg<<<(nN + 7) / 8, 256, 0, stream>>>(
        xfb, rfb, perm, ei, etype, ew, offs, (float4*)out, nN);
  } else {
    edge_scatter<<<(nE + 7) / 8, 256, 0, stream>>>(xfb, rfb, ei, etype, ew, out, nE);
  }
}

// Round 4
// 261.940 us; speedup vs baseline: 4.9427x; 1.1139x over previous
//
#include <hip/hip_runtime.h>

#define D 128
#define SCAN_B 256

typedef short bf16x8 __attribute__((ext_vector_type(8)));
typedef float f32x4 __attribute__((ext_vector_type(4)));

static __device__ __forceinline__ unsigned short f2bf(float f) {
  union { float f; unsigned u; } v; v.f = f;
  return (unsigned short)((v.u + 0x7FFF + ((v.u >> 16) & 1)) >> 16);   // RNE
}
static __device__ __forceinline__ float bf2f(unsigned short h) {
  union { unsigned u; float f; } v; v.u = ((unsigned)h) << 16;
  return v.f;
}
static __device__ __forceinline__ float bflo(unsigned u) {   // low bf16 of a u32
  union { unsigned u; float f; } v; v.u = u << 16; return v.f;
}
static __device__ __forceinline__ float bfhi(unsigned u) {   // high bf16 of a u32
  union { unsigned u; float f; } v; v.u = u & 0xFFFF0000u; return v.f;
}

// ---------------------------------------------------------------------------
// prep_kernel (fused): blocks [0,16)   : Wself/Wfwd -> bf16 MFMA-B-swizzled Wb
//                      blocks [16,+rB) : rel path (2 rel rows per block)
//                      rest            : zero offs (int4 stores)
// ---------------------------------------------------------------------------
__global__ __launch_bounds__(256) void prep_kernel(
    const float* __restrict__ Wself, const float* __restrict__ Wfwd,
    const float* __restrict__ rel, const float* __restrict__ Wr,
    unsigned short* __restrict__ Wb, unsigned short* __restrict__ rfb,
    float* __restrict__ rel_out, int* __restrict__ offs,
    int nR, int nN, int relBlocks) {
  const int tid = threadIdx.x;
  if ((int)blockIdx.x < 16) {
    // Wb[frag*512 + lane*8 + j]: frag=((mat*8+ct)*4+kt), lane(q=lane>>4,r=lane&15)
    // holds W[ct*16+r][kt*32+q*8+j]
    const int g = blockIdx.x * 256 + tid;     // 0..4095
    const int frag = g >> 6, lane = g & 63;
    const int mat = frag >> 5, ct = (frag >> 2) & 7, kt = frag & 3;
    const int q = lane >> 4, r = lane & 15;
    const float* W = mat ? Wfwd : Wself;
    const float* src = W + (ct * 16 + r) * D + kt * 32 + q * 8;
    unsigned short* dst = Wb + frag * 512 + lane * 8;
    #pragma unroll
    for (int j = 0; j < 8; ++j) dst[j] = f2bf(src[j]);
  } else if ((int)blockIdx.x < 16 + relBlocks) {
    __shared__ float row[2][D];
    const int half = tid >> 7;                 // 0/1: which rel row
    const int c = tid & 127;
    const int rr = ((int)blockIdx.x - 16) * 2 + half;
    const int r2 = (rr < nR) ? rr : nR - 1;
    row[half][c] = rel[r2 * D + c];
    __syncthreads();
    float af = 0.f, ar = 0.f;
    #pragma unroll 8
    for (int k = 0; k < D; ++k) {
      const float xv = row[half][k];
      af += xv * Wfwd[c * D + k];
      ar += xv * Wr[c * D + k];
    }
    if (rr < nR) {
      rfb[rr * D + c] = f2bf(af);
      rel_out[rr * D + c] = ar;
    }
  } else {
    const int i = ((int)blockIdx.x - 16 - relBlocks) * 256 + tid;  // int4 index
    const int e0 = i * 4;
    if (e0 < nN) {
      if (e0 + 3 < nN) ((int4*)offs)[i] = make_int4(0, 0, 0, 0);
      else { for (int k = e0; k < nN; ++k) offs[k] = 0; }
    }
  }
}

// ---------------------------------------------------------------------------
// fused_main: blocks [0,gemmBlocks): node GEMM via MFMA
//   out = x@Wself^T + bias (fp32), xfb = bf16(x@Wfwd^T). 64 nodes/block,
//   no LDS; A-frag inline fp32->bf16 (reused x16 MFMAs); B-frag 16B from Wb.
//   C/D layout: col=lane&15, row=(lane>>4)*4+reg.
// blocks [gemmBlocks, +histBlocks): dst histogram (4 edges/thread, int atomics)
//   — atomic-latency-bound, co-schedules under the MFMA blocks for free.
// ---------------------------------------------------------------------------
__global__ __launch_bounds__(256) void fused_main(
    const float* __restrict__ x, const unsigned short* __restrict__ Wb,
    const float* __restrict__ bias, const int* __restrict__ dst,
    float* __restrict__ out, unsigned short* __restrict__ xfb,
    int* __restrict__ offs, int nN, int nE, int gemmBlocks) {
  if ((int)blockIdx.x < gemmBlocks) {
    const int tid = threadIdx.x;
    const int w = tid >> 6, lane = tid & 63;
    const int q = lane >> 4, r = lane & 15;
    const int n0 = blockIdx.x * 64 + w * 16;

    f32x4 accS[8], accF[8];
    #pragma unroll
    for (int ct = 0; ct < 8; ++ct) { accS[ct] = (f32x4)0.f; accF[ct] = (f32x4)0.f; }

    int arow = n0 + r;
    if (arow >= nN) arow = nN - 1;   // clamp (stores guarded)
    const float* xrow = x + (size_t)arow * D;

    #pragma unroll
    for (int kt = 0; kt < 4; ++kt) {
      const float* xp = xrow + kt * 32 + q * 8;
      const float4 x0 = *(const float4*)xp;
      const float4 x1 = *(const float4*)(xp + 4);
      bf16x8 a;
      a[0] = (short)f2bf(x0.x); a[1] = (short)f2bf(x0.y);
      a[2] = (short)f2bf(x0.z); a[3] = (short)f2bf(x0.w);
      a[4] = (short)f2bf(x1.x); a[5] = (short)f2bf(x1.y);
      a[6] = (short)f2bf(x1.z); a[7] = (short)f2bf(x1.w);
      #pragma unroll
      for (int ct = 0; ct < 8; ++ct) {
        const bf16x8 bS = *(const bf16x8*)(Wb + ((0 * 8 + ct) * 4 + kt) * 512 + lane * 8);
        const bf16x8 bF = *(const bf16x8*)(Wb + ((1 * 8 + ct) * 4 + kt) * 512 + lane * 8);
        accS[ct] = __builtin_amdgcn_mfma_f32_16x16x32_bf16(a, bS, accS[ct], 0, 0, 0);
        accF[ct] = __builtin_amdgcn_mfma_f32_16x16x32_bf16(a, bF, accF[ct], 0, 0, 0);
      }
    }

    #pragma unroll
    for (int ct = 0; ct < 8; ++ct) {
      const int col = ct * 16 + r;
      const float bv = bias[col];
      #pragma unroll
      for (int reg = 0; reg < 4; ++reg) {
        const int row = n0 + q * 4 + reg;
        if (row < nN) {
          out[(size_t)row * D + col] = accS[ct][reg] + bv;
          xfb[(size_t)row * D + col] = f2bf(accF[ct][reg]);
        }
      }
    }
  } else {
    const int i0 = (((int)blockIdx.x - gemmBlocks) * 256 + (int)threadIdx.x) * 4;
    if (((nE & 3) == 0) && i0 + 3 < nE) {
      const int4 d4 = *(const int4*)(dst + i0);
      atomicAdd(&offs[d4.x], 1); atomicAdd(&offs[d4.y], 1);
      atomicAdd(&offs[d4.z], 1); atomicAdd(&offs[d4.w], 1);
    } else {
      for (int e = i0; e < nE && e < i0 + 4; ++e) atomicAdd(&offs[dst[e]], 1);
    }
  }
}

// ---------------------------------------------------------------------------
// exclusive scan over offs (3 small kernels, unchanged logic)
// ---------------------------------------------------------------------------
__global__ __launch_bounds__(SCAN_B) void scan_pass1(
    const int* __restrict__ deg, int* __restrict__ bsum, int n) {
  __shared__ int sd[SCAN_B];
  const int i = blockIdx.x * SCAN_B + threadIdx.x;
  sd[threadIdx.x] = (i < n) ? deg[i] : 0;
  __syncthreads();
  for (int s = SCAN_B / 2; s > 0; s >>= 1) {
    if (threadIdx.x < s) sd[threadIdx.x] += sd[threadIdx.x + s];
    __syncthreads();
  }
  if (threadIdx.x == 0) bsum[blockIdx.x] = sd[0];
}

__global__ __launch_bounds__(1024) void scan_pass2(int* __restrict__ bsum, int nb) {
  __shared__ int sd[1024];
  const int t = threadIdx.x;
  const int v = (t < nb) ? bsum[t] : 0;
  sd[t] = v;
  __syncthreads();
  for (int off = 1; off < 1024; off <<= 1) {
    const int add = (t >= off) ? sd[t - off] : 0;
    __syncthreads();
    sd[t] += add;
    __syncthreads();
  }
  if (t < nb) bsum[t] = sd[t] - v;   // exclusive
}

__global__ __launch_bounds__(SCAN_B) void scan_pass3(
    int* __restrict__ deg_offs, const int* __restrict__ bsum, int n) {
  __shared__ int sd[SCAN_B];
  const int i = blockIdx.x * SCAN_B + threadIdx.x;
  const int t = threadIdx.x;
  const int v = (i < n) ? deg_offs[i] : 0;
  sd[t] = v;
  __syncthreads();
  for (int off = 1; off < SCAN_B; off <<= 1) {
    const int add = (t >= off) ? sd[t - off] : 0;
    __syncthreads();
    sd[t] += add;
    __syncthreads();
  }
  if (i < n) deg_offs[i] = sd[t] - v + bsum[blockIdx.x];   // exclusive global
}

// ---------------------------------------------------------------------------
// fill: CSR-ordered PACKED metadata. meta[p] = {src | et<<20, bits(ew)}.
// Reads coalesced here; the 3 random reads per edge move out of the hot kernel
// and become one scattered 8B write.
// ---------------------------------------------------------------------------
__global__ void fill_kernel(const int* __restrict__ src, const int* __restrict__ dstv,
                            const int* __restrict__ et, const float* __restrict__ ew,
                            int* __restrict__ cursor, uint2* __restrict__ meta, int nE) {
  const int e = blockIdx.x * blockDim.x + threadIdx.x;
  if (e < nE) {
    const int p = atomicAdd(&cursor[dstv[e]], 1);
    meta[p] = make_uint2((unsigned)src[e] | ((unsigned)et[e] << 20),
                         __float_as_uint(ew[e]));
  }
}

// ---------------------------------------------------------------------------
// csr_agg: out[n,:] += sum_{e in bucket(n)} ew*(xfb[src]-rfb[et]).
// 16 lanes/node, uint4 (16B) bf16 gathers, coalesced packed-meta reads,
// shuffle-broadcast width 16, fp32 accumulate, one RMW of out per node.
// ---------------------------------------------------------------------------
__global__ __launch_bounds__(256) void csr_agg(
    const uint4* __restrict__ xfb4, const uint4* __restrict__ rfb4,
    const uint2* __restrict__ meta, const int* __restrict__ offs,
    float* __restrict__ out, int nN) {
  const int n = blockIdx.x * 16 + ((int)threadIdx.x >> 4);
  if (n >= nN) return;
  const int lane = threadIdx.x & 15;
  const int end = offs[n];
  const int start = (n == 0) ? 0 : offs[n - 1];

  float acc[8] = {0.f, 0.f, 0.f, 0.f, 0.f, 0.f, 0.f, 0.f};
  for (int base = start; base < end; base += 16) {
    int m = end - base; if (m > 16) m = 16;
    uint2 mv = make_uint2(0u, 0u);
    if (lane < m) mv = meta[base + lane];
    for (int j = 0; j < m; ++j) {
      const unsigned pk = (unsigned)__shfl((int)mv.x, j, 16);
      const float wgt = __uint_as_float(__shfl((int)mv.y, j, 16));
      const int s = (int)(pk & 0xFFFFFu);
      const int t = (int)(pk >> 20);
      const uint4 a = xfb4[(size_t)s * 16 + lane];
      const uint4 b = rfb4[(size_t)t * 16 + lane];
      acc[0] += wgt * (bflo(a.x) - bflo(b.x));
      acc[1] += wgt * (bfhi(a.x) - bfhi(b.x));
      acc[2] += wgt * (bflo(a.y) - bflo(b.y));
      acc[3] += wgt * (bfhi(a.y) - bfhi(b.y));
      acc[4] += wgt * (bflo(a.z) - bflo(b.z));
      acc[5] += wgt * (bfhi(a.z) - bfhi(b.z));
      acc[6] += wgt * (bflo(a.w) - bflo(b.w));
      acc[7] += wgt * (bfhi(a.w) - bfhi(b.w));
    }
  }
  float* o = out + (size_t)n * D + lane * 8;
  float4 o0 = *(const float4*)o;
  float4 o1 = *(const float4*)(o + 4);
  o0.x += acc[0]; o0.y += acc[1]; o0.z += acc[2]; o0.w += acc[3];
  o1.x += acc[4]; o1.y += acc[5]; o1.z += acc[6]; o1.w += acc[7];
  *(float4*)o = o0;
  *(float4*)(o + 4) = o1;
}

// ---------------------------------------------------------------------------
// Fallback (atomic scatter) if ws too small / sizes outgrow the packing
// ---------------------------------------------------------------------------
__global__ __launch_bounds__(256) void edge_scatter(
    const unsigned short* __restrict__ xfb, const unsigned short* __restrict__ rfb,
    const int* __restrict__ ei, const int* __restrict__ etype,
    const float* __restrict__ ew, float* __restrict__ out, int nE) {
  const int e = blockIdx.x * 8 + ((int)threadIdx.x >> 5);
  if (e >= nE) return;
  const int lane = threadIdx.x & 31;
  const int s = ei[e];
  const int d = ei[nE + e];
  const int t = etype[e];
  const float w = ew[e];
  const ushort4 a = ((const ushort4*)(xfb + (size_t)s * D))[lane];
  const ushort4 b = ((const ushort4*)(rfb + (size_t)t * D))[lane];
  float* o = out + (size_t)d * D + lane * 4;
  atomicAdd(o + 0, w * (bf2f(a.x) - bf2f(b.x)));
  atomicAdd(o + 1, w * (bf2f(a.y) - bf2f(b.y)));
  atomicAdd(o + 2, w * (bf2f(a.z) - bf2f(b.z)));
  atomicAdd(o + 3, w * (bf2f(a.w) - bf2f(b.w)));
}

// ---------------------------------------------------------------------------
extern "C" void kernel_launch(void* const* d_in, const int* in_sizes, int n_in,
                              void* d_out, int out_size, void* d_ws, size_t ws_size,
                              hipStream_t stream) {
  const float* x      = (const float*)d_in[0];
  const int*   ei     = (const int*)d_in[1];
  const int*   etype  = (const int*)d_in[2];
  const float* rel    = (const float*)d_in[3];
  const float* ew     = (const float*)d_in[4];
  const float* Wself  = (const float*)d_in[5];
  const float* Wfwd   = (const float*)d_in[6];
  const float* Wrel   = (const float*)d_in[7];
  const float* bias   = (const float*)d_in[8];

  const int nN = in_sizes[0] / D;       // 100000
  const int nE = in_sizes[2];           // 625000
  const int nR = in_sizes[3] / D;       // 200

  float* out     = (float*)d_out;
  float* rel_out = (float*)d_out + (size_t)nN * D;

  // workspace carve-up (256B-aligned)
  char* w = (char*)d_ws;
  size_t off = 0;
  auto carve = [&](size_t bytes) {
    char* p = w + off;
    off = (off + bytes + 255) & ~(size_t)255;
    return p;
  };
  unsigned short* xfb = (unsigned short*)carve((size_t)nN * D * sizeof(unsigned short));
  unsigned short* rfb = (unsigned short*)carve((size_t)nR * D * sizeof(unsigned short));
  unsigned short* Wb  = (unsigned short*)carve(2 * 8 * 4 * 512 * sizeof(unsigned short));
  int*   offs = (int*)carve((size_t)nN * sizeof(int));
  uint2* meta = (uint2*)carve((size_t)nE * sizeof(uint2));
  int*   bsum = (int*)carve(1024 * sizeof(int));
  const size_t need = off;

  const int* dst = ei + nE;
  const int nb = (nN + SCAN_B - 1) / SCAN_B;
  const int relBlocks  = (nR + 1) / 2;
  const int zeroBlocks = (nN + 1023) / 1024;
  const int gemmBlocks = (nN + 63) / 64;
  const int histBlocks = (nE + 1023) / 1024;

  const bool csr_ok = (need <= ws_size) && (nb <= 1024) &&
                      (nN < (1 << 20)) && (nR <= 4096);

  // Wb prep + rel path + zero offs (one dispatch)
  prep_kernel<<<16 + relBlocks + zeroBlocks, 256, 0, stream>>>(
      Wself, Wfwd, rel, Wrel, Wb, rfb, rel_out, offs, nR, nN, relBlocks);

  // node GEMM (MFMA) + dst histogram, co-scheduled
  fused_main<<<gemmBlocks + (csr_ok ? histBlocks : 0), 256, 0, stream>>>(
      x, Wb, bias, dst, out, xfb, offs, nN, nE, gemmBlocks);

  if (csr_ok) {
    scan_pass1<<<nb, SCAN_B, 0, stream>>>(offs, bsum, nN);
    scan_pass2<<<1, 1024, 0, stream>>>(bsum, nb);
    scan_pass3<<<nb, SCAN_B, 0, stream>>>(offs, bsum, nN);
    fill_kernel<<<(nE + 255) / 256, 256, 0, stream>>>(ei, dst, etype, ew, offs, meta, nE);
    csr_agg<<<(nN + 15) / 16, 256, 0, stream>>>(
        (const uint4*)xfb, (const uint4*)rfb, meta, offs, out, nN);
  } else {
    edge_scatter<<<(nE + 7) / 8, 256, 0, stream>>>(xfb, rfb, ei, etype, ew, out, nE);
  }
}

// Round 5
// 242.774 us; speedup vs baseline: 5.3329x; 1.0789x over previous
//
#include <hip/hip_runtime.h>

#define D 128
#define SCAN_B 256

typedef short bf16x8 __attribute__((ext_vector_type(8)));
typedef float f32x4 __attribute__((ext_vector_type(4)));

static __device__ __forceinline__ unsigned short f2bf(float f) {
  union { float f; unsigned u; } v; v.f = f;
  return (unsigned short)((v.u + 0x7FFF + ((v.u >> 16) & 1)) >> 16);   // RNE
}
static __device__ __forceinline__ float bf2f(unsigned short h) {
  union { unsigned u; float f; } v; v.u = ((unsigned)h) << 16;
  return v.f;
}
static __device__ __forceinline__ float bflo(unsigned u) {
  union { unsigned u; float f; } v; v.u = u << 16; return v.f;
}
static __device__ __forceinline__ float bfhi(unsigned u) {
  union { unsigned u; float f; } v; v.u = u & 0xFFFF0000u; return v.f;
}

// ---------------------------------------------------------------------------
// prep_kernel (fused): blocks [0,16)   : Wself/Wfwd -> bf16 MFMA-B-swizzled Wb
//                      blocks [16,+rB) : rel path (2 rel rows per block)
//                      rest            : zero offs (int4 stores)
// ---------------------------------------------------------------------------
__global__ __launch_bounds__(256) void prep_kernel(
    const float* __restrict__ Wself, const float* __restrict__ Wfwd,
    const float* __restrict__ rel, const float* __restrict__ Wr,
    unsigned short* __restrict__ Wb, unsigned short* __restrict__ rfb,
    float* __restrict__ rel_out, int* __restrict__ offs,
    int nR, int nN, int relBlocks) {
  const int tid = threadIdx.x;
  if ((int)blockIdx.x < 16) {
    // Wb[frag*512 + lane*8 + j]: frag=((mat*8+ct)*4+kt), lane(q=lane>>4,r=lane&15)
    // holds W[ct*16+r][kt*32+q*8+j]
    const int g = blockIdx.x * 256 + tid;     // 0..4095
    const int frag = g >> 6, lane = g & 63;
    const int mat = frag >> 5, ct = (frag >> 2) & 7, kt = frag & 3;
    const int q = lane >> 4, r = lane & 15;
    const float* W = mat ? Wfwd : Wself;
    const float* src = W + (ct * 16 + r) * D + kt * 32 + q * 8;
    unsigned short* dst = Wb + frag * 512 + lane * 8;
    #pragma unroll
    for (int j = 0; j < 8; ++j) dst[j] = f2bf(src[j]);
  } else if ((int)blockIdx.x < 16 + relBlocks) {
    __shared__ float row[2][D];
    const int half = tid >> 7;                 // 0/1: which rel row
    const int c = tid & 127;
    const int rr = ((int)blockIdx.x - 16) * 2 + half;
    const int r2 = (rr < nR) ? rr : nR - 1;
    row[half][c] = rel[r2 * D + c];
    __syncthreads();
    float af = 0.f, ar = 0.f;
    #pragma unroll 8
    for (int k = 0; k < D; ++k) {
      const float xv = row[half][k];
      af += xv * Wfwd[c * D + k];
      ar += xv * Wr[c * D + k];
    }
    if (rr < nR) {
      rfb[rr * D + c] = f2bf(af);
      rel_out[rr * D + c] = ar;
    }
  } else {
    const int i = ((int)blockIdx.x - 16 - relBlocks) * 256 + tid;  // int4 index
    const int e0 = i * 4;
    if (e0 < nN) {
      if (e0 + 3 < nN) ((int4*)offs)[i] = make_int4(0, 0, 0, 0);
      else { for (int k = e0; k < nN; ++k) offs[k] = 0; }
    }
  }
}

// ---------------------------------------------------------------------------
// fused_main: blocks [0,gemmBlocks): node GEMM via MFMA.
//   128 nodes/block, 4 waves; each wave owns 32 rows (two 16-row groups) —
//   two independent A-load streams = 2x memory ILP, B-frag traffic per node
//   halved. Pass decomposition (mat x col-half): live acc = 32 AGPRs instead
//   of 64, stores spread across passes. __launch_bounds__(256,4): >=4
//   waves/SIMD. C/D layout: col=lane&15, row=(lane>>4)*4+reg.
// blocks [gemmBlocks,+histBlocks): dst histogram (co-scheduled, atomic-bound).
// ---------------------------------------------------------------------------
__global__ __launch_bounds__(256, 4) void fused_main(
    const float* __restrict__ x, const unsigned short* __restrict__ Wb,
    const float* __restrict__ bias, const int* __restrict__ dst,
    float* __restrict__ out, unsigned short* __restrict__ xfb,
    int* __restrict__ offs, int nN, int nE, int gemmBlocks) {
  if ((int)blockIdx.x < gemmBlocks) {
    const int tid = threadIdx.x;
    const int w = tid >> 6, lane = tid & 63;
    const int q = lane >> 4, r = lane & 15;
    const int g0 = blockIdx.x * 128 + w * 32;     // rows g0..g0+15, g0+16..g0+31

    int row0 = g0 + r;        if (row0 >= nN) row0 = nN - 1;
    int row1 = g0 + 16 + r;   if (row1 >= nN) row1 = nN - 1;
    const float* xr0 = x + (size_t)row0 * D;
    const float* xr1 = x + (size_t)row1 * D;

    // A fragments for both row-groups, kept live across all passes
    bf16x8 a0[4], a1[4];
    #pragma unroll
    for (int kt = 0; kt < 4; ++kt) {
      const float* p0 = xr0 + kt * 32 + q * 8;
      const float* p1 = xr1 + kt * 32 + q * 8;
      const float4 u0 = *(const float4*)p0;
      const float4 u1 = *(const float4*)(p0 + 4);
      const float4 v0 = *(const float4*)p1;
      const float4 v1 = *(const float4*)(p1 + 4);
      a0[kt][0] = (short)f2bf(u0.x); a0[kt][1] = (short)f2bf(u0.y);
      a0[kt][2] = (short)f2bf(u0.z); a0[kt][3] = (short)f2bf(u0.w);
      a0[kt][4] = (short)f2bf(u1.x); a0[kt][5] = (short)f2bf(u1.y);
      a0[kt][6] = (short)f2bf(u1.z); a0[kt][7] = (short)f2bf(u1.w);
      a1[kt][0] = (short)f2bf(v0.x); a1[kt][1] = (short)f2bf(v0.y);
      a1[kt][2] = (short)f2bf(v0.z); a1[kt][3] = (short)f2bf(v0.w);
      a1[kt][4] = (short)f2bf(v1.x); a1[kt][5] = (short)f2bf(v1.y);
      a1[kt][6] = (short)f2bf(v1.z); a1[kt][7] = (short)f2bf(v1.w);
    }

    #pragma unroll
    for (int mat = 0; mat < 2; ++mat) {
      #pragma unroll
      for (int ch = 0; ch < 2; ++ch) {
        f32x4 acc0[4], acc1[4];
        #pragma unroll
        for (int c2 = 0; c2 < 4; ++c2) { acc0[c2] = (f32x4)0.f; acc1[c2] = (f32x4)0.f; }

        #pragma unroll
        for (int kt = 0; kt < 4; ++kt) {
          #pragma unroll
          for (int c2 = 0; c2 < 4; ++c2) {
            const int ct = ch * 4 + c2;
            const bf16x8 b = *(const bf16x8*)(Wb + ((mat * 8 + ct) * 4 + kt) * 512 + lane * 8);
            acc0[c2] = __builtin_amdgcn_mfma_f32_16x16x32_bf16(a0[kt], b, acc0[c2], 0, 0, 0);
            acc1[c2] = __builtin_amdgcn_mfma_f32_16x16x32_bf16(a1[kt], b, acc1[c2], 0, 0, 0);
          }
        }

        #pragma unroll
        for (int c2 = 0; c2 < 4; ++c2) {
          const int col = (ch * 4 + c2) * 16 + r;
          if (mat == 0) {
            const float bv = bias[col];
            #pragma unroll
            for (int reg = 0; reg < 4; ++reg) {
              const int ra = g0 + q * 4 + reg;
              const int rb = g0 + 16 + q * 4 + reg;
              if (ra < nN) out[(size_t)ra * D + col] = acc0[c2][reg] + bv;
              if (rb < nN) out[(size_t)rb * D + col] = acc1[c2][reg] + bv;
            }
          } else {
            #pragma unroll
            for (int reg = 0; reg < 4; ++reg) {
              const int ra = g0 + q * 4 + reg;
              const int rb = g0 + 16 + q * 4 + reg;
              if (ra < nN) xfb[(size_t)ra * D + col] = f2bf(acc0[c2][reg]);
              if (rb < nN) xfb[(size_t)rb * D + col] = f2bf(acc1[c2][reg]);
            }
          }
        }
      }
    }
  } else {
    const int i0 = (((int)blockIdx.x - gemmBlocks) * 256 + (int)threadIdx.x) * 4;
    if (((nE & 3) == 0) && i0 + 3 < nE) {
      const int4 d4 = *(const int4*)(dst + i0);
      atomicAdd(&offs[d4.x], 1); atomicAdd(&offs[d4.y], 1);
      atomicAdd(&offs[d4.z], 1); atomicAdd(&offs[d4.w], 1);
    } else {
      for (int e = i0; e < nE && e < i0 + 4; ++e) atomicAdd(&offs[dst[e]], 1);
    }
  }
}

// ---------------------------------------------------------------------------
// exclusive scan over offs (3 small kernels)
// ---------------------------------------------------------------------------
__global__ __launch_bounds__(SCAN_B) void scan_pass1(
    const int* __restrict__ deg, int* __restrict__ bsum, int n) {
  __shared__ int sd[SCAN_B];
  const int i = blockIdx.x * SCAN_B + threadIdx.x;
  sd[threadIdx.x] = (i < n) ? deg[i] : 0;
  __syncthreads();
  for (int s = SCAN_B / 2; s > 0; s >>= 1) {
    if (threadIdx.x < s) sd[threadIdx.x] += sd[threadIdx.x + s];
    __syncthreads();
  }
  if (threadIdx.x == 0) bsum[blockIdx.x] = sd[0];
}

__global__ __launch_bounds__(1024) void scan_pass2(int* __restrict__ bsum, int nb) {
  __shared__ int sd[1024];
  const int t = threadIdx.x;
  const int v = (t < nb) ? bsum[t] : 0;
  sd[t] = v;
  __syncthreads();
  for (int off = 1; off < 1024; off <<= 1) {
    const int add = (t >= off) ? sd[t - off] : 0;
    __syncthreads();
    sd[t] += add;
    __syncthreads();
  }
  if (t < nb) bsum[t] = sd[t] - v;   // exclusive
}

__global__ __launch_bounds__(SCAN_B) void scan_pass3(
    int* __restrict__ deg_offs, const int* __restrict__ bsum, int n) {
  __shared__ int sd[SCAN_B];
  const int i = blockIdx.x * SCAN_B + threadIdx.x;
  const int t = threadIdx.x;
  const int v = (i < n) ? deg_offs[i] : 0;
  sd[t] = v;
  __syncthreads();
  for (int off = 1; off < SCAN_B; off <<= 1) {
    const int add = (t >= off) ? sd[t - off] : 0;
    __syncthreads();
    sd[t] += add;
    __syncthreads();
  }
  if (i < n) deg_offs[i] = sd[t] - v + bsum[blockIdx.x];   // exclusive global
}

// ---------------------------------------------------------------------------
// fill: CSR-ordered PACKED metadata. meta[p] = {src | et<<20, bits(ew)}.
// ---------------------------------------------------------------------------
__global__ void fill_kernel(const int* __restrict__ src, const int* __restrict__ dstv,
                            const int* __restrict__ et, const float* __restrict__ ew,
                            int* __restrict__ cursor, uint2* __restrict__ meta, int nE) {
  const int e = blockIdx.x * blockDim.x + threadIdx.x;
  if (e < nE) {
    const int p = atomicAdd(&cursor[dstv[e]], 1);
    meta[p] = make_uint2((unsigned)src[e] | ((unsigned)et[e] << 20),
                         __float_as_uint(ew[e]));
  }
}

// ---------------------------------------------------------------------------
// csr_agg: out[n,:] += sum_{e in bucket(n)} ew*(xfb[src]-rfb[et]).
// 16 lanes/node, uint4 (16B) bf16 gathers, coalesced packed-meta reads,
// shuffle-broadcast width 16, fp32 accumulate, one RMW of out per node.
// ---------------------------------------------------------------------------
__global__ __launch_bounds__(256) void csr_agg(
    const uint4* __restrict__ xfb4, const uint4* __restrict__ rfb4,
    const uint2* __restrict__ meta, const int* __restrict__ offs,
    float* __restrict__ out, int nN) {
  const int n = blockIdx.x * 16 + ((int)threadIdx.x >> 4);
  if (n >= nN) return;
  const int lane = threadIdx.x & 15;
  const int end = offs[n];
  const int start = (n == 0) ? 0 : offs[n - 1];

  float acc[8] = {0.f, 0.f, 0.f, 0.f, 0.f, 0.f, 0.f, 0.f};
  for (int base = start; base < end; base += 16) {
    int m = end - base; if (m > 16) m = 16;
    uint2 mv = make_uint2(0u, 0u);
    if (lane < m) mv = meta[base + lane];
    for (int j = 0; j < m; ++j) {
      const unsigned pk = (unsigned)__shfl((int)mv.x, j, 16);
      const float wgt = __uint_as_float(__shfl((int)mv.y, j, 16));
      const int s = (int)(pk & 0xFFFFFu);
      const int t = (int)(pk >> 20);
      const uint4 a = xfb4[(size_t)s * 16 + lane];
      const uint4 b = rfb4[(size_t)t * 16 + lane];
      acc[0] += wgt * (bflo(a.x) - bflo(b.x));
      acc[1] += wgt * (bfhi(a.x) - bfhi(b.x));
      acc[2] += wgt * (bflo(a.y) - bflo(b.y));
      acc[3] += wgt * (bfhi(a.y) - bfhi(b.y));
      acc[4] += wgt * (bflo(a.z) - bflo(b.z));
      acc[5] += wgt * (bfhi(a.z) - bfhi(b.z));
      acc[6] += wgt * (bflo(a.w) - bflo(b.w));
      acc[7] += wgt * (bfhi(a.w) - bfhi(b.w));
    }
  }
  float* o = out + (size_t)n * D + lane * 8;
  float4 o0 = *(const float4*)o;
  float4 o1 = *(const float4*)(o + 4);
  o0.x += acc[0]; o0.y += acc[1]; o0.z += acc[2]; o0.w += acc[3];
  o1.x += acc[4]; o1.y += acc[5]; o1.z += acc[6]; o1.w += acc[7];
  *(float4*)o = o0;
  *(float4*)(o + 4) = o1;
}

// ---------------------------------------------------------------------------
// Fallback (atomic scatter) if ws too small / sizes outgrow the packing
// ---------------------------------------------------------------------------
__global__ __launch_bounds__(256) void edge_scatter(
    const unsigned short* __restrict__ xfb, const unsigned short* __restrict__ rfb,
    const int* __restrict__ ei, const int* __restrict__ etype,
    const float* __restrict__ ew, float* __restrict__ out, int nE) {
  const int e = blockIdx.x * 8 + ((int)threadIdx.x >> 5);
  if (e >= nE) return;
  const int lane = threadIdx.x & 31;
  const int s = ei[e];
  const int d = ei[nE + e];
  const int t = etype[e];
  const float w = ew[e];
  const ushort4 a = ((const ushort4*)(xfb + (size_t)s * D))[lane];
  const ushort4 b = ((const ushort4*)(rfb + (size_t)t * D))[lane];
  float* o = out + (size_t)d * D + lane * 4;
  atomicAdd(o + 0, w * (bf2f(a.x) - bf2f(b.x)));
  atomicAdd(o + 1, w * (bf2f(a.y) - bf2f(b.y)));
  atomicAdd(o + 2, w * (bf2f(a.z) - bf2f(b.z)));
  atomicAdd(o + 3, w * (bf2f(a.w) - bf2f(b.w)));
}

// ---------------------------------------------------------------------------
extern "C" void kernel_launch(void* const* d_in, const int* in_sizes, int n_in,
                              void* d_out, int out_size, void* d_ws, size_t ws_size,
                              hipStream_t stream) {
  const float* x      = (const float*)d_in[0];
  const int*   ei     = (const int*)d_in[1];
  const int*   etype  = (const int*)d_in[2];
  const float* rel    = (const float*)d_in[3];
  const float* ew     = (const float*)d_in[4];
  const float* Wself  = (const float*)d_in[5];
  const float* Wfwd   = (const float*)d_in[6];
  const float* Wrel   = (const float*)d_in[7];
  const float* bias   = (const float*)d_in[8];

  const int nN = in_sizes[0] / D;       // 100000
  const int nE = in_sizes[2];           // 625000
  const int nR = in_sizes[3] / D;       // 200

  float* out     = (float*)d_out;
  float* rel_out = (float*)d_out + (size_t)nN * D;

  // workspace carve-up (256B-aligned)
  char* w = (char*)d_ws;
  size_t off = 0;
  auto carve = [&](size_t bytes) {
    char* p = w + off;
    off = (off + bytes + 255) & ~(size_t)255;
    return p;
  };
  unsigned short* xfb = (unsigned short*)carve((size_t)nN * D * sizeof(unsigned short));
  unsigned short* rfb = (unsigned short*)carve((size_t)nR * D * sizeof(unsigned short));
  unsigned short* Wb  = (unsigned short*)carve(2 * 8 * 4 * 512 * sizeof(unsigned short));
  int*   offs = (int*)carve((size_t)nN * sizeof(int));
  uint2* meta = (uint2*)carve((size_t)nE * sizeof(uint2));
  int*   bsum = (int*)carve(1024 * sizeof(int));
  const size_t need = off;

  const int* dst = ei + nE;
  const int nb = (nN + SCAN_B - 1) / SCAN_B;
  const int relBlocks  = (nR + 1) / 2;
  const int zeroBlocks = (nN + 1023) / 1024;
  const int gemmBlocks = (nN + 127) / 128;
  const int histBlocks = (nE + 1023) / 1024;

  const bool csr_ok = (need <= ws_size) && (nb <= 1024) &&
                      (nN < (1 << 20)) && (nR <= 4096);

  // Wb prep + rel path + zero offs (one dispatch)
  prep_kernel<<<16 + relBlocks + zeroBlocks, 256, 0, stream>>>(
      Wself, Wfwd, rel, Wrel, Wb, rfb, rel_out, offs, nR, nN, relBlocks);

  // node GEMM (MFMA) + dst histogram, co-scheduled
  fused_main<<<gemmBlocks + (csr_ok ? histBlocks : 0), 256, 0, stream>>>(
      x, Wb, bias, dst, out, xfb, offs, nN, nE, gemmBlocks);

  if (csr_ok) {
    scan_pass1<<<nb, SCAN_B, 0, stream>>>(offs, bsum, nN);
    scan_pass2<<<1, 1024, 0, stream>>>(bsum, nb);
    scan_pass3<<<nb, SCAN_B, 0, stream>>>(offs, bsum, nN);
    fill_kernel<<<(nE + 255) / 256, 256, 0, stream>>>(ei, dst, etype, ew, offs, meta, nE);
    csr_agg<<<(nN + 15) / 16, 256, 0, stream>>>(
        (const uint4*)xfb, (const uint4*)rfb, meta, offs, out, nN);
  } else {
    edge_scatter<<<(nE + 7) / 8, 256, 0, stream>>>(xfb, rfb, ei, etype, ew, out, nE);
  }
}